// Round 1
// baseline (1145.444 us; speedup 1.0000x reference)
//
#include <hip/hip_runtime.h>
#include <hip/hip_fp16.h>

// ---------------------------------------------------------------------------
// DeterministicLSTMSensorBasedForwardDynamics on MI355X (gfx950)
//
// Shapes: B=4096, T=50, OBS=64, ACT=16, H=256 (4H=1024), OUT=64, NLAYERS=5
//
// Design (see round notes):
//  * fp16 MFMA (16x16x32) with fp32 accumulate; c-state fp32 in registers.
//  * 128 WGs x 512 threads; WG owns 32 batch rows for the whole sequence.
//  * Wave w owns h-cols [32w,32w+32); computes the MATCHING columns of all
//    four gates -> LSTM cell update is pure per-lane register math.
//  * A-panel [x_t | h | pad] in LDS, double buffered, 1 barrier/step.
//  * Weights repacked (prologue kernel) into fragment-block layout:
//    block(nt,kt) = 1KB, lane-contiguous 16B -> one dwordx4 per B-frag.
// ---------------------------------------------------------------------------

typedef _Float16 h8 __attribute__((ext_vector_type(8)));
typedef _Float16 hv4 __attribute__((ext_vector_type(4)));
typedef float f4 __attribute__((ext_vector_type(4)));

#define NB    4096
#define TSEQ  50
#define DOBS  64
#define DACT  16
#define HD    256
#define DOUT  64
#define NL    5

#define NKT   11        // K-tiles of 32 covering 352 = 80 (x) + 256 (h) + 16 (zero pad)
#define AROW  360       // LDS row stride in halves: 720B -> bank shift 20 -> 2-way (free)
#define MTILE 32
#define NWG   (NB / MTILE)   // 128
#define NTHR  512            // 8 waves

// ws layout in halves: 704 LSTM blocks, 5*128 MLP blocks, 32 Wout blocks (512 halves each)
#define WS_MLP   (704 * 512)
#define WS_WOUT  (WS_MLP + 640 * 512)
// total = 1376 * 512 halves = 1,409,024 bytes of d_ws

__device__ __forceinline__ float sigf(float x) { return 1.f / (1.f + __expf(-x)); }

// --------------------------- weight repack ---------------------------------
// One thread per (block, lane): writes 8 contiguous halves (16B).
// Block content: lane l, elem j -> W[k = kt*32 + (l>>4)*8 + j][n = nt*16 + (l&15)]
__global__ void __launch_bounds__(256) repack_kernel(
    const float* __restrict__ Wi, const float* __restrict__ Wh,
    const float* __restrict__ mlpW, const float* __restrict__ Wout,
    _Float16* __restrict__ wsW)
{
  const int gt  = blockIdx.x * 256 + threadIdx.x;   // grid is exactly 1376*64 threads
  const int gb  = gt >> 6;
  const int l   = gt & 63;
  const int l15 = l & 15;
  const int kb  = (l >> 4) * 8;
  h8 v;
  if (gb < 704) {                       // LSTM: Wcat[k][n], k<80 -> Wi, k<336 -> Wh, else 0
    const int nt = gb / NKT, kt = gb - nt * NKT;
    const int n  = nt * 16 + l15;
#pragma unroll
    for (int j = 0; j < 8; ++j) {
      const int k = kt * 32 + kb + j;
      float s = 0.f;
      if (k < 80)       s = Wi[k * 1024 + n];
      else if (k < 336) s = Wh[(k - 80) * 1024 + n];
      v[j] = (_Float16)s;
    }
  } else if (gb < 1344) {               // MLP layer weights [5][256][256]
    const int b2 = gb - 704;
    const int L  = b2 >> 7, rr = b2 & 127;
    const int nt = rr >> 3, kt = rr & 7;
    const int n  = nt * 16 + l15;
#pragma unroll
    for (int j = 0; j < 8; ++j) {
      const int k = kt * 32 + kb + j;
      v[j] = (_Float16)mlpW[(size_t)L * 65536 + k * 256 + n];
    }
  } else {                              // Wout [256][64]
    const int b3 = gb - 1344;
    const int nt = b3 >> 3, kt = b3 & 7;
    const int n  = nt * 16 + l15;
#pragma unroll
    for (int j = 0; j < 8; ++j) {
      const int k = kt * 32 + kb + j;
      v[j] = (_Float16)Wout[k * 64 + n];
    }
  }
  *(h8*)&wsW[(size_t)gb * 512 + l * 8] = v;
}

// ------------------------------ main kernel --------------------------------
__global__ void __launch_bounds__(NTHR) lstm_kernel(
    const float* __restrict__ traj, const float* __restrict__ acts,
    const float* __restrict__ bh,   const float* __restrict__ mlpb,
    const float* __restrict__ bout, const _Float16* __restrict__ wsW,
    float* __restrict__ out)
{
  __shared__ __align__(16) _Float16 As[2][MTILE * AROW];   // 2 x 23040 B

  const int tid = threadIdx.x;
  const int w   = tid >> 6;        // wave 0..7: owns h-cols [32w, 32w+32)
  const int l   = tid & 63;
  const int l15 = l & 15;
  const int lq  = l >> 4;
  const int rbase = blockIdx.x * MTILE;

  // Zero both LDS buffers: h starts at 0; pad cols (336..359) stay 0 forever.
  for (int i = tid; i < MTILE * AROW; i += NTHR) {
    As[0][i] = (_Float16)0.f;
    As[1][i] = (_Float16)0.f;
  }

  // Persistent cell state, per lane: [cb][mt][r]
  float c[2][2][4];
#pragma unroll
  for (int cb = 0; cb < 2; ++cb)
#pragma unroll
    for (int mt = 0; mt < 2; ++mt)
#pragma unroll
      for (int r = 0; r < 4; ++r) c[cb][mt][r] = 0.f;

  // Gate biases, per lane: [gate][cb]
  float bias[4][2];
#pragma unroll
  for (int g = 0; g < 4; ++g) {
    bias[g][0] = bh[g * 256 + w * 32 + l15];
    bias[g][1] = bh[g * 256 + w * 32 + 16 + l15];
  }

  __syncthreads();   // zeroing done before x_0 staging touches the same buffer

  // Stage x_0 into As[0] cols 0..79 (traj 0..63, actions 64..79)
  {
    const int r = tid >> 4, q = tid & 15;
    const float4 v = *(const float4*)&traj[(size_t)(rbase + r) * (TSEQ * DOBS) + q * 4];
    hv4 hx = { (_Float16)v.x, (_Float16)v.y, (_Float16)v.z, (_Float16)v.w };
    *(hv4*)&As[0][r * AROW + q * 4] = hx;
    As[0][r * AROW + 64 + q] = (_Float16)acts[(size_t)(rbase + r) * (TSEQ * DACT) + q];
  }
  __syncthreads();

#pragma unroll 1
  for (int t = 0; t < TSEQ; ++t) {
    const _Float16* __restrict__ buf = As[t & 1];
    _Float16* __restrict__ nbuf = As[(t & 1) ^ 1];

    // Prefetch x_{t+1} into the inactive buffer (cols 0..79; disjoint from h cols).
    // nbuf's last readers finished at the barrier ending step t-1.
    if (t + 1 < TSEQ) {
      const int r = tid >> 4, q = tid & 15;
      const float4 v = *(const float4*)&traj[(size_t)(rbase + r) * (TSEQ * DOBS) + (t + 1) * DOBS + q * 4];
      hv4 hx = { (_Float16)v.x, (_Float16)v.y, (_Float16)v.z, (_Float16)v.w };
      *(hv4*)&nbuf[r * AROW + q * 4] = hx;
      nbuf[r * AROW + 64 + q] = (_Float16)acts[(size_t)(rbase + r) * (TSEQ * DACT) + (t + 1) * DACT + q];
    }

#pragma unroll
    for (int cb = 0; cb < 2; ++cb) {
      f4 acc[4][2];   // [gate][mt]
#pragma unroll
      for (int g = 0; g < 4; ++g) {
        acc[g][0] = f4{0.f, 0.f, 0.f, 0.f};
        acc[g][1] = f4{0.f, 0.f, 0.f, 0.f};
      }

#pragma unroll
      for (int kt = 0; kt < NKT; ++kt) {
        const h8 a0 = *(const h8*)&buf[l15 * AROW + kt * 32 + lq * 8];
        const h8 a1 = *(const h8*)&buf[(16 + l15) * AROW + kt * 32 + lq * 8];
#pragma unroll
        for (int g = 0; g < 4; ++g) {
          const int nt = g * 16 + w * 2 + cb;
          const h8 bf = *(const h8*)&wsW[(size_t)(nt * NKT + kt) * 512 + l * 8];
          acc[g][0] = __builtin_amdgcn_mfma_f32_16x16x32_f16(a0, bf, acc[g][0], 0, 0, 0);
          acc[g][1] = __builtin_amdgcn_mfma_f32_16x16x32_f16(a1, bf, acc[g][1], 0, 0, 0);
        }
      }

      // Cell update: all four gates for (row,col) sit in the same lane/reg slot.
      const int colh = 80 + w * 32 + cb * 16 + l15;
#pragma unroll
      for (int mt = 0; mt < 2; ++mt) {
#pragma unroll
        for (int r = 0; r < 4; ++r) {
          const float zi = acc[0][mt][r] + bias[0][cb];
          const float zf = acc[1][mt][r] + bias[1][cb];
          const float zg = acc[2][mt][r] + bias[2][cb];
          const float zo = acc[3][mt][r] + bias[3][cb];
          const float ig = sigf(zi);
          const float fg = sigf(zf);
          const float gg = zg * sigf(zg);       // silu
          const float og = sigf(zo);
          const float cn = fg * c[cb][mt][r] + ig * gg;
          c[cb][mt][r] = cn;
          const float hh = og * cn * sigf(cn);  // o * silu(c)
          nbuf[(mt * 16 + lq * 4 + r) * AROW + colh] = (_Float16)hh;
        }
      }
    }
    __syncthreads();   // one barrier per step
  }

  // ---------------- MLP head ----------------
  // Final h is in As[0] cols 80..335 (t=49 wrote nbuf=As[0]). Move to As[1] cols 0..255.
  for (int i = tid; i < MTILE * HD; i += NTHR) {
    const int r = i >> 8, cc = i & 255;
    As[1][r * AROW + cc] = As[0][r * AROW + 80 + cc];
  }
  __syncthreads();

#pragma unroll 1
  for (int L = 0; L < NL; ++L) {
    const _Float16* __restrict__ in = As[(L & 1) ^ 1];   // L0 reads As[1]
    _Float16* __restrict__ ob = As[L & 1];
    const _Float16* __restrict__ wl = wsW + WS_MLP + (size_t)L * (128 * 512);
    float bcol[2];
    bcol[0] = mlpb[L * HD + w * 32 + l15];
    bcol[1] = mlpb[L * HD + w * 32 + 16 + l15];

    f4 acc[2][2];   // [cb][mt]
#pragma unroll
    for (int cb = 0; cb < 2; ++cb) {
      acc[cb][0] = f4{0.f, 0.f, 0.f, 0.f};
      acc[cb][1] = f4{0.f, 0.f, 0.f, 0.f};
    }
#pragma unroll
    for (int kt = 0; kt < 8; ++kt) {
      const h8 a0 = *(const h8*)&in[l15 * AROW + kt * 32 + lq * 8];
      const h8 a1 = *(const h8*)&in[(16 + l15) * AROW + kt * 32 + lq * 8];
#pragma unroll
      for (int cb = 0; cb < 2; ++cb) {
        const int nt = w * 2 + cb;
        const h8 bf = *(const h8*)&wl[(size_t)(nt * 8 + kt) * 512 + l * 8];
        acc[cb][0] = __builtin_amdgcn_mfma_f32_16x16x32_f16(a0, bf, acc[cb][0], 0, 0, 0);
        acc[cb][1] = __builtin_amdgcn_mfma_f32_16x16x32_f16(a1, bf, acc[cb][1], 0, 0, 0);
      }
    }
#pragma unroll
    for (int cb = 0; cb < 2; ++cb) {
#pragma unroll
      for (int mt = 0; mt < 2; ++mt) {
#pragma unroll
        for (int r = 0; r < 4; ++r) {
          const float z = acc[cb][mt][r] + bcol[cb];
          const float a = z * sigf(z);          // silu
          ob[(mt * 16 + lq * 4 + r) * AROW + w * 32 + cb * 16 + l15] = (_Float16)a;
        }
      }
    }
    __syncthreads();
  }

  // Output layer: final activations in As[(NL-1)&1] = As[0]. N=64 -> waves 0..3.
  if (w < 4) {
    const _Float16* __restrict__ wo = wsW + WS_WOUT;
    const float bo = bout[w * 16 + l15];
    f4 acc0 = f4{0.f, 0.f, 0.f, 0.f};
    f4 acc1 = f4{0.f, 0.f, 0.f, 0.f};
#pragma unroll
    for (int kt = 0; kt < 8; ++kt) {
      const h8 a0 = *(const h8*)&As[0][l15 * AROW + kt * 32 + lq * 8];
      const h8 a1 = *(const h8*)&As[0][(16 + l15) * AROW + kt * 32 + lq * 8];
      const h8 bf = *(const h8*)&wo[(size_t)(w * 8 + kt) * 512 + l * 8];
      acc0 = __builtin_amdgcn_mfma_f32_16x16x32_f16(a0, bf, acc0, 0, 0, 0);
      acc1 = __builtin_amdgcn_mfma_f32_16x16x32_f16(a1, bf, acc1, 0, 0, 0);
    }
#pragma unroll
    for (int r = 0; r < 4; ++r) {
      out[(size_t)(rbase + lq * 4 + r) * DOUT + w * 16 + l15] = acc0[r] + bo;
      out[(size_t)(rbase + 16 + lq * 4 + r) * DOUT + w * 16 + l15] = acc1[r] + bo;
    }
  }
}

// ------------------------------- launcher ----------------------------------
extern "C" void kernel_launch(void* const* d_in, const int* in_sizes, int n_in,
                              void* d_out, int out_size, void* d_ws, size_t ws_size,
                              hipStream_t stream)
{
  const float* traj = (const float*)d_in[0];
  const float* acts = (const float*)d_in[1];
  const float* Wi   = (const float*)d_in[2];
  const float* Wh   = (const float*)d_in[3];
  const float* bh   = (const float*)d_in[4];
  const float* mlpW = (const float*)d_in[5];
  const float* mlpb = (const float*)d_in[6];
  const float* Wout = (const float*)d_in[7];
  const float* bout = (const float*)d_in[8];
  _Float16* wsW = (_Float16*)d_ws;   // needs 1,409,024 bytes of workspace

  repack_kernel<<<344, 256, 0, stream>>>(Wi, Wh, mlpW, Wout, wsW);   // 344*256 = 1376*64
  lstm_kernel<<<NWG, NTHR, 0, stream>>>(traj, acts, bh, mlpb, bout, wsW, (float*)d_out);
}

// Round 2
// 551.934 us; speedup vs baseline: 2.0753x; 2.0753x over previous
//
#include <hip/hip_runtime.h>
#include <hip/hip_fp16.h>

// ---------------------------------------------------------------------------
// DeterministicLSTMSensorBasedForwardDynamics on MI355X (gfx950) — round 2
//
// Round-1 finding: kernel ran at the external-traffic rate (1.27 TB/s, FETCH
// 1.3 GB) re-reading the t-invariant weights every step. Fix: make ~half the
// per-CU weight working set resident on-chip for the whole sequence:
//   * 24 blocks/wave (96 VGPR) register-resident   (cb0, kt0..5)
//   * 12 blocks/wave LDS-resident (96 KB/CU)       (cb0, kt6..8)
//   * 52 blocks/wave streamed via 12-slot rolling reg buffer (deep MLP)
// __launch_bounds__(512,2) -> 256 VGPR/wave. Dynamic LDS 141 KB.
// ---------------------------------------------------------------------------

typedef _Float16 h8 __attribute__((ext_vector_type(8)));
typedef _Float16 hv4 __attribute__((ext_vector_type(4)));
typedef float f4 __attribute__((ext_vector_type(4)));

#define NB    4096
#define TSEQ  50
#define DOBS  64
#define DACT  16
#define HD    256
#define DOUT  64
#define NL    5

#define NKT   11        // K-tiles of 32 covering 352 = 80 (x) + 256 (h) + 16 pad
#define AROW  360       // LDS A-row stride in halves (720 B -> 2-way bank alias, free)
#define MTILE 32
#define NWG   (NB / MTILE)   // 128
#define NTHR  512            // 8 waves

// ws layout in halves (written by repack_kernel)
#define WS_MLP   (704 * 512)
#define WS_WOUT  (WS_MLP + 640 * 512)

// LDS layout (halves): As0 | As1 | Wcache(96 blocks)
#define LDS_AS1   (MTILE * AROW)        // 11520
#define LDS_WC    (2 * MTILE * AROW)    // 23040
#define WCB       12                    // LDS-resident blocks per wave
#define LDS_HALVES (LDS_WC + 8 * WCB * 512)   // 23040 + 49152 = 72192
#define LDS_BYTES  (LDS_HALVES * 2)           // 144384  (<= 160 KiB)
static_assert(LDS_BYTES <= 160 * 1024, "LDS overflow");

// streaming
#define SB_P     12    // rolling buffer slots (48 VGPRs)
#define NSTREAM  52    // streamed blocks per wave per step

__device__ __forceinline__ float sigf(float x) { return 1.f / (1.f + __expf(-x)); }

// stream order c -> block offset (halves) relative to (w*2*NKT*512):
// c in [0,8): cb0, kt = 9 + c/4, g = c&3 ; c in [8,52): cb1, kt = (c-8)/4, g = (c-8)&3
__device__ constexpr int soff(int c) {
  int g, cb, kt;
  if (c < 8) { cb = 0; kt = 9 + (c >> 2); g = c & 3; }
  else       { int j = c - 8; cb = 1; kt = j >> 2; g = j & 3; }
  return ((g * 16 + cb) * NKT + kt) * 512;
}

// --------------------------- weight repack ---------------------------------
__global__ void __launch_bounds__(256) repack_kernel(
    const float* __restrict__ Wi, const float* __restrict__ Wh,
    const float* __restrict__ mlpW, const float* __restrict__ Wout,
    _Float16* __restrict__ wsW)
{
  const int gt  = blockIdx.x * 256 + threadIdx.x;
  const int gb  = gt >> 6;
  const int l   = gt & 63;
  const int l15 = l & 15;
  const int kb  = (l >> 4) * 8;
  h8 v;
  if (gb < 704) {                       // LSTM: Wcat[k][n], k<80 -> Wi, k<336 -> Wh, else 0
    const int nt = gb / NKT, kt = gb - nt * NKT;
    const int n  = nt * 16 + l15;
#pragma unroll
    for (int j = 0; j < 8; ++j) {
      const int k = kt * 32 + kb + j;
      float s = 0.f;
      if (k < 80)       s = Wi[k * 1024 + n];
      else if (k < 336) s = Wh[(k - 80) * 1024 + n];
      v[j] = (_Float16)s;
    }
  } else if (gb < 1344) {               // MLP layer weights [5][256][256]
    const int b2 = gb - 704;
    const int L  = b2 >> 7, rr = b2 & 127;
    const int nt = rr >> 3, kt = rr & 7;
    const int n  = nt * 16 + l15;
#pragma unroll
    for (int j = 0; j < 8; ++j) {
      const int k = kt * 32 + kb + j;
      v[j] = (_Float16)mlpW[(size_t)L * 65536 + k * 256 + n];
    }
  } else {                              // Wout [256][64]
    const int b3 = gb - 1344;
    const int nt = b3 >> 3, kt = b3 & 7;
    const int n  = nt * 16 + l15;
#pragma unroll
    for (int j = 0; j < 8; ++j) {
      const int k = kt * 32 + kb + j;
      v[j] = (_Float16)Wout[k * 64 + n];
    }
  }
  *(h8*)&wsW[(size_t)gb * 512 + l * 8] = v;
}

// ------------------------------ main kernel --------------------------------
__global__ void __launch_bounds__(NTHR, 2) lstm_kernel(
    const float* __restrict__ traj, const float* __restrict__ acts,
    const float* __restrict__ bh,   const float* __restrict__ mlpb,
    const float* __restrict__ bout, const _Float16* __restrict__ wsW,
    float* __restrict__ out)
{
  extern __shared__ __align__(16) _Float16 lds[];
  _Float16* As0 = lds;
  _Float16* As1 = lds + LDS_AS1;
  _Float16* Wc  = lds + LDS_WC;

  const int tid = threadIdx.x;
  const int w   = tid >> 6;        // wave 0..7: owns h-cols [32w, 32w+32)
  const int l   = tid & 63;
  const int l15 = l & 15;
  const int lq  = l >> 4;
  const int rbase = blockIdx.x * MTILE;

  // Zero both A buffers (h starts 0; pad cols 336..359 stay 0 forever).
  for (int i = tid; i < 2 * MTILE * AROW; i += NTHR) lds[i] = (_Float16)0.f;

  // LDS-resident weight cache: 12 blocks/wave = (cb0, kt6..8, g0..3)
#pragma unroll
  for (int j = 0; j < WCB; ++j) {
    const int g = j & 3, kt = 6 + (j >> 2);
    const int blk = (g * 16 + w * 2) * NKT + kt;
    const h8 v = *(const h8*)&wsW[(size_t)blk * 512 + l * 8];
    *(h8*)&Wc[(w * WCB + j) * 512 + l * 8] = v;
  }

  // Register-resident: 24 blocks/wave = (cb0, kt0..5, g0..3)
  h8 rw[24];
#pragma unroll
  for (int kt = 0; kt < 6; ++kt)
#pragma unroll
    for (int g = 0; g < 4; ++g)
      rw[kt * 4 + g] = *(const h8*)&wsW[(size_t)((g * 16 + w * 2) * NKT + kt) * 512 + l * 8];

  // Persistent cell state + biases
  float c[2][2][4];
#pragma unroll
  for (int cb = 0; cb < 2; ++cb)
#pragma unroll
    for (int mt = 0; mt < 2; ++mt)
#pragma unroll
      for (int r = 0; r < 4; ++r) c[cb][mt][r] = 0.f;

  float bias[4][2];
#pragma unroll
  for (int g = 0; g < 4; ++g) {
    bias[g][0] = bh[g * 256 + w * 32 + l15];
    bias[g][1] = bh[g * 256 + w * 32 + 16 + l15];
  }

  __syncthreads();

  // Stage x_0 into As0 cols 0..79
  {
    const int r = tid >> 4, q = tid & 15;
    const float4 v = *(const float4*)&traj[(size_t)(rbase + r) * (TSEQ * DOBS) + q * 4];
    hv4 hx = { (_Float16)v.x, (_Float16)v.y, (_Float16)v.z, (_Float16)v.w };
    *(hv4*)&As0[r * AROW + q * 4] = hx;
    As0[r * AROW + 64 + q] = (_Float16)acts[(size_t)(rbase + r) * (TSEQ * DACT) + q];
  }
  __syncthreads();

  unsigned long long wbits = (unsigned long long)(const void*)wsW;

#pragma unroll 1
  for (int t = 0; t < TSEQ; ++t) {
    // Launder the stream base so loop-invariant streamed loads can't be
    // hoisted/CSE'd across iterations (would explode register pressure).
    asm volatile("" : "+s"(wbits));
    const _Float16* wst = (const _Float16*)wbits;
    const _Float16* buf  = (t & 1) ? As1 : As0;
    _Float16*       nbuf = (t & 1) ? As0 : As1;

    // Prefetch x_{t+1} into inactive buffer (cols 0..79).
    if (t + 1 < TSEQ) {
      const int r = tid >> 4, q = tid & 15;
      const float4 v = *(const float4*)&traj[(size_t)(rbase + r) * (TSEQ * DOBS) + (t + 1) * DOBS + q * 4];
      hv4 hx = { (_Float16)v.x, (_Float16)v.y, (_Float16)v.z, (_Float16)v.w };
      *(hv4*)&nbuf[r * AROW + q * 4] = hx;
      nbuf[r * AROW + 64 + q] = (_Float16)acts[(size_t)(rbase + r) * (TSEQ * DACT) + (t + 1) * DACT + q];
    }

    // Per-wave stream base (covers the w*2 part of nt) and rolling buffer.
    const _Float16* wlb = wst + (size_t)(w * 2 * NKT) * 512 + l * 8;
    h8 sb[SB_P];
#pragma unroll
    for (int cc = 0; cc < SB_P; ++cc) sb[cc] = *(const h8*)&wlb[soff(cc)];

    // ---------------- cb = 0 (fully resident except kt9,10) ----------------
    {
      f4 acc[4][2];
#pragma unroll
      for (int g = 0; g < 4; ++g) { acc[g][0] = f4{0.f,0.f,0.f,0.f}; acc[g][1] = f4{0.f,0.f,0.f,0.f}; }

#pragma unroll
      for (int kt = 0; kt < NKT; ++kt) {
        const h8 a0 = *(const h8*)&buf[l15 * AROW + kt * 32 + lq * 8];
        const h8 a1 = *(const h8*)&buf[(16 + l15) * AROW + kt * 32 + lq * 8];
#pragma unroll
        for (int g = 0; g < 4; ++g) {
          h8 bf;
          if (kt < 6)       bf = rw[kt * 4 + g];
          else if (kt < 9)  bf = *(const h8*)&Wc[(w * WCB + (kt - 6) * 4 + g) * 512 + l * 8];
          else              bf = sb[(kt - 9) * 4 + g];
          acc[g][0] = __builtin_amdgcn_mfma_f32_16x16x32_f16(a0, bf, acc[g][0], 0, 0, 0);
          acc[g][1] = __builtin_amdgcn_mfma_f32_16x16x32_f16(a1, bf, acc[g][1], 0, 0, 0);
          if (kt >= 9) {   // reissue c+12 into the freed slot
            const int cc = (kt - 9) * 4 + g;
            sb[cc] = *(const h8*)&wlb[soff(cc + SB_P)];
          }
        }
      }

      const int colh = 80 + w * 32 + l15;   // cb=0
#pragma unroll
      for (int mt = 0; mt < 2; ++mt)
#pragma unroll
        for (int r = 0; r < 4; ++r) {
          const float zi = acc[0][mt][r] + bias[0][0];
          const float zf = acc[1][mt][r] + bias[1][0];
          const float zg = acc[2][mt][r] + bias[2][0];
          const float zo = acc[3][mt][r] + bias[3][0];
          const float ig = sigf(zi), fg = sigf(zf), og = sigf(zo);
          const float gg = zg * sigf(zg);
          const float cn = fg * c[0][mt][r] + ig * gg;
          c[0][mt][r] = cn;
          nbuf[(mt * 16 + lq * 4 + r) * AROW + colh] = (_Float16)(og * cn * sigf(cn));
        }
    }

    // ---------------- cb = 1 (fully streamed) ----------------
    {
      f4 acc[4][2];
#pragma unroll
      for (int g = 0; g < 4; ++g) { acc[g][0] = f4{0.f,0.f,0.f,0.f}; acc[g][1] = f4{0.f,0.f,0.f,0.f}; }

#pragma unroll
      for (int kt = 0; kt < NKT; ++kt) {
        const h8 a0 = *(const h8*)&buf[l15 * AROW + kt * 32 + lq * 8];
        const h8 a1 = *(const h8*)&buf[(16 + l15) * AROW + kt * 32 + lq * 8];
#pragma unroll
        for (int g = 0; g < 4; ++g) {
          const int cc = 8 + kt * 4 + g;
          const int s  = cc % SB_P;
          const h8 bf = sb[s];
          acc[g][0] = __builtin_amdgcn_mfma_f32_16x16x32_f16(a0, bf, acc[g][0], 0, 0, 0);
          acc[g][1] = __builtin_amdgcn_mfma_f32_16x16x32_f16(a1, bf, acc[g][1], 0, 0, 0);
          if (cc + SB_P < NSTREAM) sb[s] = *(const h8*)&wlb[soff(cc + SB_P)];
        }
      }

      const int colh = 80 + w * 32 + 16 + l15;   // cb=1
#pragma unroll
      for (int mt = 0; mt < 2; ++mt)
#pragma unroll
        for (int r = 0; r < 4; ++r) {
          const float zi = acc[0][mt][r] + bias[0][1];
          const float zf = acc[1][mt][r] + bias[1][1];
          const float zg = acc[2][mt][r] + bias[2][1];
          const float zo = acc[3][mt][r] + bias[3][1];
          const float ig = sigf(zi), fg = sigf(zf), og = sigf(zo);
          const float gg = zg * sigf(zg);
          const float cn = fg * c[1][mt][r] + ig * gg;
          c[1][mt][r] = cn;
          nbuf[(mt * 16 + lq * 4 + r) * AROW + colh] = (_Float16)(og * cn * sigf(cn));
        }
    }

    __syncthreads();   // one barrier per step
  }

  // ---------------- MLP head ----------------
  // Final h is in As0 cols 80..335 (t=49 wrote nbuf=As0). Move to As1 cols 0..255.
  for (int i = tid; i < MTILE * HD; i += NTHR) {
    const int r = i >> 8, cc = i & 255;
    As1[r * AROW + cc] = As0[r * AROW + 80 + cc];
  }
  __syncthreads();

#pragma unroll 1
  for (int L = 0; L < NL; ++L) {
    const _Float16* __restrict__ in = (L & 1) ? As0 : As1;
    _Float16* __restrict__ ob       = (L & 1) ? As1 : As0;
    const _Float16* __restrict__ wl = wsW + WS_MLP + (size_t)L * (128 * 512);
    float bcol[2];
    bcol[0] = mlpb[L * HD + w * 32 + l15];
    bcol[1] = mlpb[L * HD + w * 32 + 16 + l15];

    f4 acc[2][2];   // [cb][mt]
#pragma unroll
    for (int cb = 0; cb < 2; ++cb) {
      acc[cb][0] = f4{0.f,0.f,0.f,0.f};
      acc[cb][1] = f4{0.f,0.f,0.f,0.f};
    }
#pragma unroll
    for (int kt = 0; kt < 8; ++kt) {
      const h8 a0 = *(const h8*)&in[l15 * AROW + kt * 32 + lq * 8];
      const h8 a1 = *(const h8*)&in[(16 + l15) * AROW + kt * 32 + lq * 8];
#pragma unroll
      for (int cb = 0; cb < 2; ++cb) {
        const int nt = w * 2 + cb;
        const h8 bf = *(const h8*)&wl[(size_t)(nt * 8 + kt) * 512 + l * 8];
        acc[cb][0] = __builtin_amdgcn_mfma_f32_16x16x32_f16(a0, bf, acc[cb][0], 0, 0, 0);
        acc[cb][1] = __builtin_amdgcn_mfma_f32_16x16x32_f16(a1, bf, acc[cb][1], 0, 0, 0);
      }
    }
#pragma unroll
    for (int cb = 0; cb < 2; ++cb)
#pragma unroll
      for (int mt = 0; mt < 2; ++mt)
#pragma unroll
        for (int r = 0; r < 4; ++r) {
          const float z = acc[cb][mt][r] + bcol[cb];
          ob[(mt * 16 + lq * 4 + r) * AROW + w * 32 + cb * 16 + l15] = (_Float16)(z * sigf(z));
        }
    __syncthreads();
  }

  // Output layer: final activations in As0 (NL=5 odd -> last ob = As0). N=64 -> waves 0..3.
  if (w < 4) {
    const _Float16* __restrict__ wo = wsW + WS_WOUT;
    const float bo = bout[w * 16 + l15];
    f4 acc0 = f4{0.f,0.f,0.f,0.f};
    f4 acc1 = f4{0.f,0.f,0.f,0.f};
#pragma unroll
    for (int kt = 0; kt < 8; ++kt) {
      const h8 a0 = *(const h8*)&As0[l15 * AROW + kt * 32 + lq * 8];
      const h8 a1 = *(const h8*)&As0[(16 + l15) * AROW + kt * 32 + lq * 8];
      const h8 bf = *(const h8*)&wo[(size_t)(w * 8 + kt) * 512 + l * 8];
      acc0 = __builtin_amdgcn_mfma_f32_16x16x32_f16(a0, bf, acc0, 0, 0, 0);
      acc1 = __builtin_amdgcn_mfma_f32_16x16x32_f16(a1, bf, acc1, 0, 0, 0);
    }
#pragma unroll
    for (int r = 0; r < 4; ++r) {
      out[(size_t)(rbase + lq * 4 + r) * DOUT + w * 16 + l15] = acc0[r] + bo;
      out[(size_t)(rbase + 16 + lq * 4 + r) * DOUT + w * 16 + l15] = acc1[r] + bo;
    }
  }
}

// ------------------------------- launcher ----------------------------------
extern "C" void kernel_launch(void* const* d_in, const int* in_sizes, int n_in,
                              void* d_out, int out_size, void* d_ws, size_t ws_size,
                              hipStream_t stream)
{
  const float* traj = (const float*)d_in[0];
  const float* acts = (const float*)d_in[1];
  const float* Wi   = (const float*)d_in[2];
  const float* Wh   = (const float*)d_in[3];
  const float* bh   = (const float*)d_in[4];
  const float* mlpW = (const float*)d_in[5];
  const float* mlpb = (const float*)d_in[6];
  const float* Wout = (const float*)d_in[7];
  const float* bout = (const float*)d_in[8];
  _Float16* wsW = (_Float16*)d_ws;   // needs 1,409,024 bytes of workspace

  // Opt-in to >64 KB dynamic LDS (idempotent; same work every call).
  (void)hipFuncSetAttribute((const void*)lstm_kernel,
                            hipFuncAttributeMaxDynamicSharedMemorySize, LDS_BYTES);

  repack_kernel<<<344, 256, 0, stream>>>(Wi, Wh, mlpW, Wout, wsW);
  lstm_kernel<<<NWG, NTHR, LDS_BYTES, stream>>>(traj, acts, bh, mlpb, bout, wsW, (float*)d_out);
}

// Round 3
// 383.536 us; speedup vs baseline: 2.9865x; 1.4391x over previous
//
#include <hip/hip_runtime.h>
#include <hip/hip_fp16.h>

// ---------------------------------------------------------------------------
// DeterministicLSTMSensorBasedForwardDynamics on MI355X (gfx950) — round 3
//
// Round-2 findings: FETCH collapsed to 38 MB (weights L2-resident) but dur
// only halved: latency-bound at Occupancy 11.6% (128 WGs = half the CUs),
// and VGPR_Count=120 proved the compiler rematerialized rw[] instead of
// keeping it register-resident. Round-3 fixes:
//   * MTILE=16, 256 WGs -> all 256 CUs active (per-CU stream unchanged).
//   * Per-step asm "memory" clobber -> rw[28] CANNOT be re-loaded -> pinned.
//   * cb0 fully on-chip (28 reg + 16 LDS blocks/wave); stream = 44 (cb1).
//   * x(t+1) prefetched to registers, LDS store deferred to end of step;
//     manual even/odd unroll makes As0/As1 compile-time distinct.
// ---------------------------------------------------------------------------

typedef _Float16 h8 __attribute__((ext_vector_type(8)));
typedef _Float16 hv4 __attribute__((ext_vector_type(4)));
typedef float f4 __attribute__((ext_vector_type(4)));

#define NB    4096
#define TSEQ  50
#define DOBS  64
#define DACT  16
#define HD    256
#define DOUT  64
#define NL    5

#define NKT   11        // K-tiles of 32 covering 352 = 80 (x) + 256 (h) + 16 pad
#define AROW  360       // LDS A-row stride in halves (uniform bank spread for b128)
#define MTILE 16
#define NWG   (NB / MTILE)   // 256
#define NTHR  512            // 8 waves

// ws layout in halves (written by repack_kernel)
#define WS_MLP   (704 * 512)
#define WS_WOUT  (WS_MLP + 640 * 512)

// LDS layout (halves): As0 | As1 | Wcache(8 waves x WCB blocks)
#define LDS_AS     (MTILE * AROW)      // 5760 per panel
#define LDS_WCOFF  (2 * LDS_AS)        // 11520
#define WCB        16                  // LDS-resident blocks per wave (cb0 kt7..10)
#define LDS_HALVES (LDS_WCOFF + 8 * WCB * 512)   // 11520 + 65536 = 77056
#define LDS_BYTES  (LDS_HALVES * 2)              // 154112  (<= 160 KiB)
static_assert(LDS_BYTES <= 160 * 1024, "LDS overflow");

// streaming: cb1 only, 44 blocks/wave/step through a 12-slot rolling reg buffer
#define SB_P     12
#define NSTREAM  44

__device__ __forceinline__ float sigf(float x) { return 1.f / (1.f + __expf(-x)); }

// stream order c (= kt*4+g over cb1) -> block offset in halves rel. to wave base
__device__ constexpr int soff(int c) {
  const int g = c & 3, kt = c >> 2;
  return (((g * 16 + 1) * NKT) + kt) * 512;
}

// --------------------------- weight repack ---------------------------------
__global__ void __launch_bounds__(256) repack_kernel(
    const float* __restrict__ Wi, const float* __restrict__ Wh,
    const float* __restrict__ mlpW, const float* __restrict__ Wout,
    _Float16* __restrict__ wsW)
{
  const int gt  = blockIdx.x * 256 + threadIdx.x;
  const int gb  = gt >> 6;
  const int l   = gt & 63;
  const int l15 = l & 15;
  const int kb  = (l >> 4) * 8;
  h8 v;
  if (gb < 704) {                       // LSTM: Wcat[k][n], k<80 -> Wi, k<336 -> Wh, else 0
    const int nt = gb / NKT, kt = gb - nt * NKT;
    const int n  = nt * 16 + l15;
#pragma unroll
    for (int j = 0; j < 8; ++j) {
      const int k = kt * 32 + kb + j;
      float s = 0.f;
      if (k < 80)       s = Wi[k * 1024 + n];
      else if (k < 336) s = Wh[(k - 80) * 1024 + n];
      v[j] = (_Float16)s;
    }
  } else if (gb < 1344) {               // MLP layer weights [5][256][256]
    const int b2 = gb - 704;
    const int L  = b2 >> 7, rr = b2 & 127;
    const int nt = rr >> 3, kt = rr & 7;
    const int n  = nt * 16 + l15;
#pragma unroll
    for (int j = 0; j < 8; ++j) {
      const int k = kt * 32 + kb + j;
      v[j] = (_Float16)mlpW[(size_t)L * 65536 + k * 256 + n];
    }
  } else {                              // Wout [256][64]
    const int b3 = gb - 1344;
    const int nt = b3 >> 3, kt = b3 & 7;
    const int n  = nt * 16 + l15;
#pragma unroll
    for (int j = 0; j < 8; ++j) {
      const int k = kt * 32 + kb + j;
      v[j] = (_Float16)Wout[k * 64 + n];
    }
  }
  *(h8*)&wsW[(size_t)gb * 512 + l * 8] = v;
}

// ------------------------------ main kernel --------------------------------
__global__ void __launch_bounds__(NTHR, 2) lstm_kernel(
    const float* __restrict__ traj, const float* __restrict__ acts,
    const float* __restrict__ bh,   const float* __restrict__ mlpb,
    const float* __restrict__ bout, const _Float16* __restrict__ wsW,
    float* __restrict__ out)
{
  extern __shared__ __align__(16) _Float16 lds[];
  _Float16* As0 = lds;
  _Float16* As1 = lds + LDS_AS;
  _Float16* Wc  = lds + LDS_WCOFF;

  const int tid = threadIdx.x;
  const int w   = tid >> 6;        // wave 0..7: owns h-cols [32w, 32w+32)
  const int l   = tid & 63;
  const int l15 = l & 15;
  const int lq  = l >> 4;
  const int rbase = blockIdx.x * MTILE;

  // Zero both A panels (h starts 0; pad cols 336..359 stay 0 forever).
  for (int i = tid; i < 2 * LDS_AS; i += NTHR) lds[i] = (_Float16)0.f;

  // LDS-resident: 16 blocks/wave = (cb0, kt7..10, g0..3)
#pragma unroll
  for (int j = 0; j < WCB; ++j) {
    const int g = j & 3, kt = 7 + (j >> 2);
    const h8 v = *(const h8*)&wsW[(size_t)((g * 16 + w * 2) * NKT + kt) * 512 + l * 8];
    *(h8*)&Wc[(w * WCB + j) * 512 + l * 8] = v;
  }

  // Register-resident: 28 blocks/wave = (cb0, kt0..6, g0..3).
  // The per-step "memory" clobber below makes re-loading these illegal.
  h8 rw[28];
#pragma unroll
  for (int kt = 0; kt < 7; ++kt)
#pragma unroll
    for (int g = 0; g < 4; ++g)
      rw[kt * 4 + g] = *(const h8*)&wsW[(size_t)((g * 16 + w * 2) * NKT + kt) * 512 + l * 8];

  // Persistent cell state + biases
  float c[2][4];
#pragma unroll
  for (int cb = 0; cb < 2; ++cb)
#pragma unroll
    for (int r = 0; r < 4; ++r) c[cb][r] = 0.f;

  float bias[4][2];
#pragma unroll
  for (int g = 0; g < 4; ++g) {
    bias[g][0] = bh[g * 256 + w * 32 + l15];
    bias[g][1] = bh[g * 256 + w * 32 + 16 + l15];
  }

  __syncthreads();

  // Stage x_0 into As0 cols 0..79 (traj via 256 threads, acts via the other 256)
  if (tid < 256) {
    const int r = tid >> 4, q = tid & 15;
    const float4 v = *(const float4*)&traj[(size_t)(rbase + r) * (TSEQ * DOBS) + q * 4];
    hv4 hx = { (_Float16)v.x, (_Float16)v.y, (_Float16)v.z, (_Float16)v.w };
    *(hv4*)&As0[r * AROW + q * 4] = hx;
  } else {
    const int r = (tid - 256) >> 4, q = (tid - 256) & 15;
    As0[r * AROW + 64 + q] = (_Float16)acts[(size_t)(rbase + r) * (TSEQ * DACT) + q];
  }
  __syncthreads();

  unsigned long long wbits = (unsigned long long)(const void*)wsW;

  auto step = [&](int t, const _Float16* buf, _Float16* nbuf) {
    // Memory clobber: (a) stream loads can't be hoisted/CSE'd across steps,
    // (b) rw[] can't be rematerialized from wsW -> stays register-resident.
    asm volatile("" : "+s"(wbits) : : "memory");
    const _Float16* wst = (const _Float16*)wbits;
    const _Float16* wlb = wst + (size_t)(w * 2 * NKT) * 512 + l * 8;

    // x(t+1): load to registers now, store to LDS at end of step.
    float4 xv; float xa;
    const bool havex = (t + 1 < TSEQ);
    if (havex) {
      if (tid < 256) {
        const int r = tid >> 4, q = tid & 15;
        xv = *(const float4*)&traj[(size_t)(rbase + r) * (TSEQ * DOBS) + (t + 1) * DOBS + q * 4];
      } else {
        const int r = (tid - 256) >> 4, q = (tid - 256) & 15;
        xa = acts[(size_t)(rbase + r) * (TSEQ * DACT) + (t + 1) * DACT + q];
      }
    }

    // Prime the cb1 stream (covered by cb0's on-chip compute).
    h8 sb[SB_P];
#pragma unroll
    for (int cc = 0; cc < SB_P; ++cc) sb[cc] = *(const h8*)&wlb[soff(cc)];

    // ---------------- cb = 0: fully on-chip (28 reg + 16 LDS blocks) -------
    {
      f4 acc[4];
#pragma unroll
      for (int g = 0; g < 4; ++g) acc[g] = f4{0.f, 0.f, 0.f, 0.f};
#pragma unroll
      for (int kt = 0; kt < NKT; ++kt) {
        const h8 a0 = *(const h8*)&buf[l15 * AROW + kt * 32 + lq * 8];
#pragma unroll
        for (int g = 0; g < 4; ++g) {
          h8 bf;
          if (kt < 7) bf = rw[kt * 4 + g];
          else        bf = *(const h8*)&Wc[(w * WCB + (kt - 7) * 4 + g) * 512 + l * 8];
          acc[g] = __builtin_amdgcn_mfma_f32_16x16x32_f16(a0, bf, acc[g], 0, 0, 0);
        }
      }
      const int colh = 80 + w * 32 + l15;
#pragma unroll
      for (int r = 0; r < 4; ++r) {
        const float zi = acc[0][r] + bias[0][0];
        const float zf = acc[1][r] + bias[1][0];
        const float zg = acc[2][r] + bias[2][0];
        const float zo = acc[3][r] + bias[3][0];
        const float ig = sigf(zi), fg = sigf(zf), og = sigf(zo);
        const float gg = zg * sigf(zg);
        const float cn = fg * c[0][r] + ig * gg;
        c[0][r] = cn;
        nbuf[(lq * 4 + r) * AROW + colh] = (_Float16)(og * cn * sigf(cn));
      }
    }

    // ---------------- cb = 1: streamed (44 blocks, 12-slot rolling) --------
    {
      f4 acc[4];
#pragma unroll
      for (int g = 0; g < 4; ++g) acc[g] = f4{0.f, 0.f, 0.f, 0.f};
#pragma unroll
      for (int kt = 0; kt < NKT; ++kt) {
        const h8 a0 = *(const h8*)&buf[l15 * AROW + kt * 32 + lq * 8];
#pragma unroll
        for (int g = 0; g < 4; ++g) {
          const int cc = kt * 4 + g;
          const int s  = cc % SB_P;
          const h8 bf = sb[s];
          acc[g] = __builtin_amdgcn_mfma_f32_16x16x32_f16(a0, bf, acc[g], 0, 0, 0);
          if (cc + SB_P < NSTREAM) sb[s] = *(const h8*)&wlb[soff(cc + SB_P)];
        }
      }
      const int colh = 80 + w * 32 + 16 + l15;
#pragma unroll
      for (int r = 0; r < 4; ++r) {
        const float zi = acc[0][r] + bias[0][1];
        const float zf = acc[1][r] + bias[1][1];
        const float zg = acc[2][r] + bias[2][1];
        const float zo = acc[3][r] + bias[3][1];
        const float ig = sigf(zi), fg = sigf(zf), og = sigf(zo);
        const float gg = zg * sigf(zg);
        const float cn = fg * c[1][r] + ig * gg;
        c[1][r] = cn;
        nbuf[(lq * 4 + r) * AROW + colh] = (_Float16)(og * cn * sigf(cn));
      }
    }

    // Deferred x(t+1) store into nbuf cols 0..79.
    if (havex) {
      if (tid < 256) {
        const int r = tid >> 4, q = tid & 15;
        hv4 hx = { (_Float16)xv.x, (_Float16)xv.y, (_Float16)xv.z, (_Float16)xv.w };
        *(hv4*)&nbuf[r * AROW + q * 4] = hx;
      } else {
        const int r = (tid - 256) >> 4, q = (tid - 256) & 15;
        nbuf[r * AROW + 64 + q] = (_Float16)xa;
      }
    }
  };

#pragma unroll 1
  for (int t = 0; t < TSEQ; t += 2) {
    step(t, As0, As1);       // compile-time distinct panels: scheduler can
    __syncthreads();         // reorder nbuf writes vs buf reads freely
    step(t + 1, As1, As0);
    __syncthreads();
  }

  // ---------------- MLP head ----------------
  // Final h in As0 cols 80..335 (t=49 wrote As0). Move to As1 cols 0..255.
  for (int i = tid; i < MTILE * HD; i += NTHR) {
    const int r = i >> 8, cc = i & 255;
    As1[r * AROW + cc] = As0[r * AROW + 80 + cc];
  }
  __syncthreads();

#pragma unroll 1
  for (int L = 0; L < NL; ++L) {
    const _Float16* in = (L & 1) ? As0 : As1;
    _Float16*       ob = (L & 1) ? As1 : As0;
    const _Float16* wl = wsW + WS_MLP + (size_t)L * (128 * 512);
    float bcol[2];
    bcol[0] = mlpb[L * HD + w * 32 + l15];
    bcol[1] = mlpb[L * HD + w * 32 + 16 + l15];

    f4 acc[2];
    acc[0] = f4{0.f, 0.f, 0.f, 0.f};
    acc[1] = f4{0.f, 0.f, 0.f, 0.f};
#pragma unroll
    for (int kt = 0; kt < 8; ++kt) {
      const h8 a0 = *(const h8*)&in[l15 * AROW + kt * 32 + lq * 8];
#pragma unroll
      for (int cb = 0; cb < 2; ++cb) {
        const h8 bf = *(const h8*)&wl[(size_t)((w * 2 + cb) * 8 + kt) * 512 + l * 8];
        acc[cb] = __builtin_amdgcn_mfma_f32_16x16x32_f16(a0, bf, acc[cb], 0, 0, 0);
      }
    }
#pragma unroll
    for (int cb = 0; cb < 2; ++cb)
#pragma unroll
      for (int r = 0; r < 4; ++r) {
        const float z = acc[cb][r] + bcol[cb];
        ob[(lq * 4 + r) * AROW + w * 32 + cb * 16 + l15] = (_Float16)(z * sigf(z));
      }
    __syncthreads();
  }

  // Output layer: final activations in As0 (NL=5 odd). N=64 -> waves 0..3.
  if (w < 4) {
    const _Float16* wo = wsW + WS_WOUT;
    const float bo = bout[w * 16 + l15];
    f4 acc0 = f4{0.f, 0.f, 0.f, 0.f};
#pragma unroll
    for (int kt = 0; kt < 8; ++kt) {
      const h8 a0 = *(const h8*)&As0[l15 * AROW + kt * 32 + lq * 8];
      const h8 bf = *(const h8*)&wo[(size_t)(w * 8 + kt) * 512 + l * 8];
      acc0 = __builtin_amdgcn_mfma_f32_16x16x32_f16(a0, bf, acc0, 0, 0, 0);
    }
#pragma unroll
    for (int r = 0; r < 4; ++r)
      out[(size_t)(rbase + lq * 4 + r) * DOUT + w * 16 + l15] = acc0[r] + bo;
  }
}

// ------------------------------- launcher ----------------------------------
extern "C" void kernel_launch(void* const* d_in, const int* in_sizes, int n_in,
                              void* d_out, int out_size, void* d_ws, size_t ws_size,
                              hipStream_t stream)
{
  const float* traj = (const float*)d_in[0];
  const float* acts = (const float*)d_in[1];
  const float* Wi   = (const float*)d_in[2];
  const float* Wh   = (const float*)d_in[3];
  const float* bh   = (const float*)d_in[4];
  const float* mlpW = (const float*)d_in[5];
  const float* mlpb = (const float*)d_in[6];
  const float* Wout = (const float*)d_in[7];
  const float* bout = (const float*)d_in[8];
  _Float16* wsW = (_Float16*)d_ws;   // needs 1,409,024 bytes of workspace

  (void)hipFuncSetAttribute((const void*)lstm_kernel,
                            hipFuncAttributeMaxDynamicSharedMemorySize, LDS_BYTES);

  repack_kernel<<<344, 256, 0, stream>>>(Wi, Wh, mlpW, Wout, wsW);
  lstm_kernel<<<NWG, NTHR, LDS_BYTES, stream>>>(traj, acts, bh, mlpb, bout, wsW, (float*)d_out);
}

// Round 4
// 337.044 us; speedup vs baseline: 3.3985x; 1.1379x over previous
//
#include <hip/hip_runtime.h>
#include <hip/hip_fp16.h>

// ---------------------------------------------------------------------------
// DeterministicLSTMSensorBasedForwardDynamics on MI355X (gfx950) — round 4
//
// Round-3 findings: occupancy fix landed (23%, dur 494->338) but VALUBusy=47%
// became the top pipe. Cause: sigf = 1/(1+exp) compiles WITHOUT fast-math ->
// full v_div_scale/v_div_fmas/v_div_fixup sequence (~11 instrs) x 5 sigmoids
// x 8 outputs/lane/step. VGPR_Count=120 means rw[] lives in AGPRs (unified
// file, MFMA reads B from AGPR) — combined budget ~248/256 is FULL, so this
// round changes ONLY the activation math:
//   * sig(x) = v_rcp_f32(1 + v_exp_f32(-x*log2e))  — 4 instrs, 1-ulp.
// Everything else identical to round 3.
// ---------------------------------------------------------------------------

typedef _Float16 h8 __attribute__((ext_vector_type(8)));
typedef _Float16 hv4 __attribute__((ext_vector_type(4)));
typedef float f4 __attribute__((ext_vector_type(4)));

#define NB    4096
#define TSEQ  50
#define DOBS  64
#define DACT  16
#define HD    256
#define DOUT  64
#define NL    5

#define NKT   11        // K-tiles of 32 covering 352 = 80 (x) + 256 (h) + 16 pad
#define AROW  360       // LDS A-row stride in halves
#define MTILE 16
#define NWG   (NB / MTILE)   // 256
#define NTHR  512            // 8 waves

// ws layout in halves (written by repack_kernel)
#define WS_MLP   (704 * 512)
#define WS_WOUT  (WS_MLP + 640 * 512)

// LDS layout (halves): As0 | As1 | Wcache(8 waves x WCB blocks)
#define LDS_AS     (MTILE * AROW)      // 5760 per panel
#define LDS_WCOFF  (2 * LDS_AS)        // 11520
#define WCB        16                  // LDS-resident blocks per wave (cb0 kt7..10)
#define LDS_HALVES (LDS_WCOFF + 8 * WCB * 512)   // 77056
#define LDS_BYTES  (LDS_HALVES * 2)              // 154112  (<= 160 KiB)
static_assert(LDS_BYTES <= 160 * 1024, "LDS overflow");

// streaming: cb1 only, 44 blocks/wave/step through a 12-slot rolling reg buffer
#define SB_P     12
#define NSTREAM  44

// sigmoid via native v_exp_f32 + v_rcp_f32 (1-ulp each; fp16 weights dominate
// the error budget). Avoids the correctly-rounded-division sequence entirely.
__device__ __forceinline__ float sigf(float x) {
  const float e = __builtin_amdgcn_exp2f(x * -1.44269504088896f);
  return __builtin_amdgcn_rcpf(1.f + e);
}

// stream order c (= kt*4+g over cb1) -> block offset in halves rel. to wave base
__device__ constexpr int soff(int c) {
  const int g = c & 3, kt = c >> 2;
  return (((g * 16 + 1) * NKT) + kt) * 512;
}

// --------------------------- weight repack ---------------------------------
__global__ void __launch_bounds__(256) repack_kernel(
    const float* __restrict__ Wi, const float* __restrict__ Wh,
    const float* __restrict__ mlpW, const float* __restrict__ Wout,
    _Float16* __restrict__ wsW)
{
  const int gt  = blockIdx.x * 256 + threadIdx.x;
  const int gb  = gt >> 6;
  const int l   = gt & 63;
  const int l15 = l & 15;
  const int kb  = (l >> 4) * 8;
  h8 v;
  if (gb < 704) {                       // LSTM: Wcat[k][n], k<80 -> Wi, k<336 -> Wh, else 0
    const int nt = gb / NKT, kt = gb - nt * NKT;
    const int n  = nt * 16 + l15;
#pragma unroll
    for (int j = 0; j < 8; ++j) {
      const int k = kt * 32 + kb + j;
      float s = 0.f;
      if (k < 80)       s = Wi[k * 1024 + n];
      else if (k < 336) s = Wh[(k - 80) * 1024 + n];
      v[j] = (_Float16)s;
    }
  } else if (gb < 1344) {               // MLP layer weights [5][256][256]
    const int b2 = gb - 704;
    const int L  = b2 >> 7, rr = b2 & 127;
    const int nt = rr >> 3, kt = rr & 7;
    const int n  = nt * 16 + l15;
#pragma unroll
    for (int j = 0; j < 8; ++j) {
      const int k = kt * 32 + kb + j;
      v[j] = (_Float16)mlpW[(size_t)L * 65536 + k * 256 + n];
    }
  } else {                              // Wout [256][64]
    const int b3 = gb - 1344;
    const int nt = b3 >> 3, kt = b3 & 7;
    const int n  = nt * 16 + l15;
#pragma unroll
    for (int j = 0; j < 8; ++j) {
      const int k = kt * 32 + kb + j;
      v[j] = (_Float16)Wout[k * 64 + n];
    }
  }
  *(h8*)&wsW[(size_t)gb * 512 + l * 8] = v;
}

// ------------------------------ main kernel --------------------------------
__global__ void __launch_bounds__(NTHR, 2) lstm_kernel(
    const float* __restrict__ traj, const float* __restrict__ acts,
    const float* __restrict__ bh,   const float* __restrict__ mlpb,
    const float* __restrict__ bout, const _Float16* __restrict__ wsW,
    float* __restrict__ out)
{
  extern __shared__ __align__(16) _Float16 lds[];
  _Float16* As0 = lds;
  _Float16* As1 = lds + LDS_AS;
  _Float16* Wc  = lds + LDS_WCOFF;

  const int tid = threadIdx.x;
  const int w   = tid >> 6;        // wave 0..7: owns h-cols [32w, 32w+32)
  const int l   = tid & 63;
  const int l15 = l & 15;
  const int lq  = l >> 4;
  const int rbase = blockIdx.x * MTILE;

  // Zero both A panels (h starts 0; pad cols 336..359 stay 0 forever).
  for (int i = tid; i < 2 * LDS_AS; i += NTHR) lds[i] = (_Float16)0.f;

  // LDS-resident: 16 blocks/wave = (cb0, kt7..10, g0..3)
#pragma unroll
  for (int j = 0; j < WCB; ++j) {
    const int g = j & 3, kt = 7 + (j >> 2);
    const h8 v = *(const h8*)&wsW[(size_t)((g * 16 + w * 2) * NKT + kt) * 512 + l * 8];
    *(h8*)&Wc[(w * WCB + j) * 512 + l * 8] = v;
  }

  // Register-resident: 28 blocks/wave = (cb0, kt0..6, g0..3) — lives in AGPRs.
  h8 rw[28];
#pragma unroll
  for (int kt = 0; kt < 7; ++kt)
#pragma unroll
    for (int g = 0; g < 4; ++g)
      rw[kt * 4 + g] = *(const h8*)&wsW[(size_t)((g * 16 + w * 2) * NKT + kt) * 512 + l * 8];

  // Persistent cell state + biases
  float c[2][4];
#pragma unroll
  for (int cb = 0; cb < 2; ++cb)
#pragma unroll
    for (int r = 0; r < 4; ++r) c[cb][r] = 0.f;

  float bias[4][2];
#pragma unroll
  for (int g = 0; g < 4; ++g) {
    bias[g][0] = bh[g * 256 + w * 32 + l15];
    bias[g][1] = bh[g * 256 + w * 32 + 16 + l15];
  }

  __syncthreads();

  // Stage x_0 into As0 cols 0..79 (traj via waves 0-3, acts via waves 4-7)
  if (tid < 256) {
    const int r = tid >> 4, q = tid & 15;
    const float4 v = *(const float4*)&traj[(size_t)(rbase + r) * (TSEQ * DOBS) + q * 4];
    hv4 hx = { (_Float16)v.x, (_Float16)v.y, (_Float16)v.z, (_Float16)v.w };
    *(hv4*)&As0[r * AROW + q * 4] = hx;
  } else {
    const int r = (tid - 256) >> 4, q = (tid - 256) & 15;
    As0[r * AROW + 64 + q] = (_Float16)acts[(size_t)(rbase + r) * (TSEQ * DACT) + q];
  }
  __syncthreads();

  unsigned long long wbits = (unsigned long long)(const void*)wsW;

  auto step = [&](int t, const _Float16* buf, _Float16* nbuf) {
    // Memory clobber: stream loads can't be hoisted/CSE'd across steps and
    // rw[] can't be legally rematerialized from wsW.
    asm volatile("" : "+s"(wbits) : : "memory");
    const _Float16* wst = (const _Float16*)wbits;
    const _Float16* wlb = wst + (size_t)(w * 2 * NKT) * 512 + l * 8;

    // x(t+1): load to registers now, store to LDS at end of step.
    float4 xv; float xa;
    const bool havex = (t + 1 < TSEQ);
    if (havex) {
      if (tid < 256) {
        const int r = tid >> 4, q = tid & 15;
        xv = *(const float4*)&traj[(size_t)(rbase + r) * (TSEQ * DOBS) + (t + 1) * DOBS + q * 4];
      } else {
        const int r = (tid - 256) >> 4, q = (tid - 256) & 15;
        xa = acts[(size_t)(rbase + r) * (TSEQ * DACT) + (t + 1) * DACT + q];
      }
    }

    // Prime the cb1 stream (covered by cb0's on-chip compute).
    h8 sb[SB_P];
#pragma unroll
    for (int cc = 0; cc < SB_P; ++cc) sb[cc] = *(const h8*)&wlb[soff(cc)];

    // ---------------- cb = 0: fully on-chip (28 reg + 16 LDS blocks) -------
    {
      f4 acc[4];
#pragma unroll
      for (int g = 0; g < 4; ++g) acc[g] = f4{0.f, 0.f, 0.f, 0.f};
#pragma unroll
      for (int kt = 0; kt < NKT; ++kt) {
        const h8 a0 = *(const h8*)&buf[l15 * AROW + kt * 32 + lq * 8];
#pragma unroll
        for (int g = 0; g < 4; ++g) {
          h8 bf;
          if (kt < 7) bf = rw[kt * 4 + g];
          else        bf = *(const h8*)&Wc[(w * WCB + (kt - 7) * 4 + g) * 512 + l * 8];
          acc[g] = __builtin_amdgcn_mfma_f32_16x16x32_f16(a0, bf, acc[g], 0, 0, 0);
        }
      }
      const int colh = 80 + w * 32 + l15;
#pragma unroll
      for (int r = 0; r < 4; ++r) {
        const float zi = acc[0][r] + bias[0][0];
        const float zf = acc[1][r] + bias[1][0];
        const float zg = acc[2][r] + bias[2][0];
        const float zo = acc[3][r] + bias[3][0];
        const float ig = sigf(zi), fg = sigf(zf), og = sigf(zo);
        const float gg = zg * sigf(zg);
        const float cn = fg * c[0][r] + ig * gg;
        c[0][r] = cn;
        nbuf[(lq * 4 + r) * AROW + colh] = (_Float16)(og * cn * sigf(cn));
      }
    }

    // ---------------- cb = 1: streamed (44 blocks, 12-slot rolling) --------
    {
      f4 acc[4];
#pragma unroll
      for (int g = 0; g < 4; ++g) acc[g] = f4{0.f, 0.f, 0.f, 0.f};
#pragma unroll
      for (int kt = 0; kt < NKT; ++kt) {
        const h8 a0 = *(const h8*)&buf[l15 * AROW + kt * 32 + lq * 8];
#pragma unroll
        for (int g = 0; g < 4; ++g) {
          const int cc = kt * 4 + g;
          const int s  = cc % SB_P;
          const h8 bf = sb[s];
          acc[g] = __builtin_amdgcn_mfma_f32_16x16x32_f16(a0, bf, acc[g], 0, 0, 0);
          if (cc + SB_P < NSTREAM) sb[s] = *(const h8*)&wlb[soff(cc + SB_P)];
        }
      }
      const int colh = 80 + w * 32 + 16 + l15;
#pragma unroll
      for (int r = 0; r < 4; ++r) {
        const float zi = acc[0][r] + bias[0][1];
        const float zf = acc[1][r] + bias[1][1];
        const float zg = acc[2][r] + bias[2][1];
        const float zo = acc[3][r] + bias[3][1];
        const float ig = sigf(zi), fg = sigf(zf), og = sigf(zo);
        const float gg = zg * sigf(zg);
        const float cn = fg * c[1][r] + ig * gg;
        c[1][r] = cn;
        nbuf[(lq * 4 + r) * AROW + colh] = (_Float16)(og * cn * sigf(cn));
      }
    }

    // Deferred x(t+1) store into nbuf cols 0..79.
    if (havex) {
      if (tid < 256) {
        const int r = tid >> 4, q = tid & 15;
        hv4 hx = { (_Float16)xv.x, (_Float16)xv.y, (_Float16)xv.z, (_Float16)xv.w };
        *(hv4*)&nbuf[r * AROW + q * 4] = hx;
      } else {
        const int r = (tid - 256) >> 4, q = (tid - 256) & 15;
        nbuf[r * AROW + 64 + q] = (_Float16)xa;
      }
    }
  };

#pragma unroll 1
  for (int t = 0; t < TSEQ; t += 2) {
    step(t, As0, As1);
    __syncthreads();
    step(t + 1, As1, As0);
    __syncthreads();
  }

  // ---------------- MLP head ----------------
  // Final h in As0 cols 80..335. Move to As1 cols 0..255.
  for (int i = tid; i < MTILE * HD; i += NTHR) {
    const int r = i >> 8, cc = i & 255;
    As1[r * AROW + cc] = As0[r * AROW + 80 + cc];
  }
  __syncthreads();

#pragma unroll 1
  for (int L = 0; L < NL; ++L) {
    const _Float16* in = (L & 1) ? As0 : As1;
    _Float16*       ob = (L & 1) ? As1 : As0;
    const _Float16* wl = wsW + WS_MLP + (size_t)L * (128 * 512);
    float bcol[2];
    bcol[0] = mlpb[L * HD + w * 32 + l15];
    bcol[1] = mlpb[L * HD + w * 32 + 16 + l15];

    f4 acc[2];
    acc[0] = f4{0.f, 0.f, 0.f, 0.f};
    acc[1] = f4{0.f, 0.f, 0.f, 0.f};
#pragma unroll
    for (int kt = 0; kt < 8; ++kt) {
      const h8 a0 = *(const h8*)&in[l15 * AROW + kt * 32 + lq * 8];
#pragma unroll
      for (int cb = 0; cb < 2; ++cb) {
        const h8 bf = *(const h8*)&wl[(size_t)((w * 2 + cb) * 8 + kt) * 512 + l * 8];
        acc[cb] = __builtin_amdgcn_mfma_f32_16x16x32_f16(a0, bf, acc[cb], 0, 0, 0);
      }
    }
#pragma unroll
    for (int cb = 0; cb < 2; ++cb)
#pragma unroll
      for (int r = 0; r < 4; ++r) {
        const float z = acc[cb][r] + bcol[cb];
        ob[(lq * 4 + r) * AROW + w * 32 + cb * 16 + l15] = (_Float16)(z * sigf(z));
      }
    __syncthreads();
  }

  // Output layer: final activations in As0 (NL=5 odd). N=64 -> waves 0..3.
  if (w < 4) {
    const _Float16* wo = wsW + WS_WOUT;
    const float bo = bout[w * 16 + l15];
    f4 acc0 = f4{0.f, 0.f, 0.f, 0.f};
#pragma unroll
    for (int kt = 0; kt < 8; ++kt) {
      const h8 a0 = *(const h8*)&As0[l15 * AROW + kt * 32 + lq * 8];
      const h8 bf = *(const h8*)&wo[(size_t)(w * 8 + kt) * 512 + l * 8];
      acc0 = __builtin_amdgcn_mfma_f32_16x16x32_f16(a0, bf, acc0, 0, 0, 0);
    }
#pragma unroll
    for (int r = 0; r < 4; ++r)
      out[(size_t)(rbase + lq * 4 + r) * DOUT + w * 16 + l15] = acc0[r] + bo;
  }
}

// ------------------------------- launcher ----------------------------------
extern "C" void kernel_launch(void* const* d_in, const int* in_sizes, int n_in,
                              void* d_out, int out_size, void* d_ws, size_t ws_size,
                              hipStream_t stream)
{
  const float* traj = (const float*)d_in[0];
  const float* acts = (const float*)d_in[1];
  const float* Wi   = (const float*)d_in[2];
  const float* Wh   = (const float*)d_in[3];
  const float* bh   = (const float*)d_in[4];
  const float* mlpW = (const float*)d_in[5];
  const float* mlpb = (const float*)d_in[6];
  const float* Wout = (const float*)d_in[7];
  const float* bout = (const float*)d_in[8];
  _Float16* wsW = (_Float16*)d_ws;   // needs 1,409,024 bytes of workspace

  (void)hipFuncSetAttribute((const void*)lstm_kernel,
                            hipFuncAttributeMaxDynamicSharedMemorySize, LDS_BYTES);

  repack_kernel<<<344, 256, 0, stream>>>(Wi, Wh, mlpW, Wout, wsW);
  lstm_kernel<<<NWG, NTHR, LDS_BYTES, stream>>>(traj, acts, bh, mlpb, bout, wsW, (float*)d_out);
}